// Round 1
// baseline (1256.558 us; speedup 1.0000x reference)
//
#include <hip/hip_runtime.h>

typedef unsigned int uint;
typedef unsigned short ushort;

typedef short bfrag __attribute__((ext_vector_type(8)));   // 8 x bf16 (4 VGPRs)
typedef float f32x4 __attribute__((ext_vector_type(4)));

__device__ __forceinline__ ushort f2bf(float f) {
  uint u = __float_as_uint(f);
  u = (u + 0x7FFFu + ((u >> 16) & 1u)) >> 16;   // RNE
  return (ushort)u;
}
__device__ __forceinline__ float bf2f(ushort h) {
  return __uint_as_float(((uint)h) << 16);
}
__device__ __forceinline__ float sigmoidf(float t) {
  return 1.0f / (1.0f + __expf(-t));
}

// ---------------------------------------------------------------------------
// Prep: pack Wq|Wk|Wv (fp32 [H][256][64]) into bf16 MFMA-B-fragment order:
//   wb[gnt][kk][lane][j] = W[k = kk*32 + (lane>>4)*8 + j][n = gnt*16 + (lane&15)]
// where gnt = head*12 + (head-local n-tile), head cols: Q 0-63 | K 64-127 | V 128-191.
// Also W1T[j][c] = W1[c][j].
// ---------------------------------------------------------------------------
__global__ void prep_kernel(const float* __restrict__ Wq, const float* __restrict__ Wk,
                            const float* __restrict__ Wv, const float* __restrict__ W1,
                            ushort* __restrict__ wb, float* __restrict__ w1t) {
  int idx = blockIdx.x * 256 + threadIdx.x;
  if (idx < 196608) {
    int j    = idx & 7;
    int lane = (idx >> 3) & 63;
    int kk   = (idx >> 9) & 7;
    int gnt  = idx >> 12;                 // 0..47
    int head = gnt / 12;
    int nh   = (gnt % 12) * 16 + (lane & 15);   // 0..191 within head
    int k    = kk * 32 + (lane >> 4) * 8 + j;   // 0..255
    int sel  = nh >> 6, d = nh & 63;
    const float* W = (sel == 0) ? Wq : ((sel == 1) ? Wk : Wv);
    wb[idx] = f2bf(W[(head * 256 + k) * 64 + d]);
  }
  if (idx < 4096) {
    int j = idx >> 8, c = idx & 255;
    w1t[idx] = W1[c * 16 + j];
  }
}

// ---------------------------------------------------------------------------
// Fused: per block 16 samples (80 x-rows).
//  - stage x fp32->bf16 into swizzled LDS (one barrier, K=256 resident)
//  - per head: 80x192 MFMA GEMM (A from LDS, B frags from L2-resident pack),
//    +bias -> QKV LDS (bf16, swizzled), 5x5 attention -> w[5] -> s += w.V
//  - SE gate: r = relu(s@W1T), g = sigmoid(r@W2 + b2), out = g*s
// LDS: x 40960 + qkv 30720 + s 8192 + scratch 1984 = 81856 B -> 2 blocks/CU.
// ---------------------------------------------------------------------------
__global__ __launch_bounds__(256, 2)
void fused_kernel(const float* __restrict__ x,
                  const float* __restrict__ bq, const float* __restrict__ bk,
                  const float* __restrict__ bv,
                  const ushort* __restrict__ wb, const float* __restrict__ w1t,
                  const float* __restrict__ b1, const float* __restrict__ W2,
                  const float* __restrict__ b2, float* __restrict__ out) {
  __shared__ ushort xlds[20480];   // 80 rows x 256 bf16, 16B-chunk XOR swizzle
  __shared__ ushort qkv[15360];    // 80 rows x 192 bf16, swizzled
  __shared__ ushort sbuf[4096];    // s: 16 samples x 256 bf16
  __shared__ float  scratch[496];  // sc [16][26]=416 | wgt [16][5]=80 ; rbuf aliases sc in gate

  const int tid  = threadIdx.x;
  const int lane = tid & 63;
  const int wave = tid >> 6;
  const int ln   = lane & 15;
  const int quad = lane >> 4;
  const int blk  = blockIdx.x;

  // ---- stage x tile: 20480 floats, fully coalesced float4, cvt to bf16
  {
    const float* xb = x + (size_t)blk * 20480;
#pragma unroll
    for (int it = 0; it < 20; ++it) {
      int f = it * 1024 + tid * 4;
      float4 v = *(const float4*)(xb + f);
      int row = f >> 8;
      int col = f & 255;
      int ch = col >> 3;
      int half = (col >> 2) & 1;
      int phys = ch ^ (row & 7);
      uint2 p;
      p.x = (uint)f2bf(v.x) | ((uint)f2bf(v.y) << 16);
      p.y = (uint)f2bf(v.z) | ((uint)f2bf(v.w) << 16);
      *(uint2*)(&xlds[row * 256 + phys * 8 + half * 4]) = p;
    }
  }
  __syncthreads();

  const int sample = tid >> 4;   // 0..15
  const int u      = tid & 15;   // 0..15
  float* sc  = scratch;          // [16][26] alpha
  float* wgt = scratch + 416;    // [16][5]

  for (int head = 0; head < 4; ++head) {
    f32x4 acc[5][3];
#pragma unroll
    for (int mt = 0; mt < 5; ++mt)
#pragma unroll
      for (int nt = 0; nt < 3; ++nt)
        acc[mt][nt] = (f32x4){0.f, 0.f, 0.f, 0.f};

    // ---- K-loop: 8 steps of 32. A: ds_read_b128; B: global dwordx4 (L2)
#pragma unroll
    for (int kk = 0; kk < 8; ++kk) {
      bfrag a[5], b[3];
      int cb = kk * 4 + quad;
#pragma unroll
      for (int mt = 0; mt < 5; ++mt) {
        int row = mt * 16 + ln;
        int off = row * 256 + ((cb ^ (row & 7)) << 3);
        a[mt] = *(const bfrag*)(&xlds[off]);
      }
#pragma unroll
      for (int nt = 0; nt < 3; ++nt) {
        int goff = (((head * 12 + wave * 3 + nt) * 8 + kk) * 64 + lane) * 8;
        b[nt] = *(const bfrag*)(wb + goff);
      }
#pragma unroll
      for (int nt = 0; nt < 3; ++nt)
#pragma unroll
        for (int mt = 0; mt < 5; ++mt)
          acc[mt][nt] = __builtin_amdgcn_mfma_f32_16x16x32_bf16(a[mt], b[nt], acc[mt][nt], 0, 0, 0);
    }

    // ---- C->LDS: add bias, bf16, swizzled. C layout: col=lane&15, row=quad*4+r
#pragma unroll
    for (int nt = 0; nt < 3; ++nt) {
      int ncol = wave * 48 + nt * 16 + ln;      // 0..191 within head
      int sel = ncol >> 6, d = ncol & 63;
      const float* bp = (sel == 0) ? bq : ((sel == 1) ? bk : bv);
      float bias = bp[head * 64 + d];
#pragma unroll
      for (int mt = 0; mt < 5; ++mt) {
#pragma unroll
        for (int r = 0; r < 4; ++r) {
          int row = mt * 16 + quad * 4 + r;
          int e = row * 192 + (((ncol >> 3) ^ (row & 7)) << 3) + (ncol & 7);
          qkv[e] = f2bf(acc[mt][nt][r] + bias);
        }
      }
    }
    __syncthreads();

    // ---- attention A: thread (sample, l=u<5): S row, softmax -> alpha to sc
    if (u < 5) {
      int rq = sample * 5 + u;
      float S[5] = {0.f, 0.f, 0.f, 0.f, 0.f};
      for (int d = 0; d < 64; d += 4) {
        float q0, q1, q2, q3;
        {
          uint2 v = *(const uint2*)(&qkv[rq * 192 + (((d >> 3) ^ (rq & 7)) << 3) + (d & 7)]);
          q0 = bf2f((ushort)(v.x & 0xffff)); q1 = bf2f((ushort)(v.x >> 16));
          q2 = bf2f((ushort)(v.y & 0xffff)); q3 = bf2f((ushort)(v.y >> 16));
        }
#pragma unroll
        for (int m = 0; m < 5; ++m) {
          int rk = sample * 5 + m;
          int col = 64 + d;
          uint2 v = *(const uint2*)(&qkv[rk * 192 + (((col >> 3) ^ (rk & 7)) << 3) + (col & 7)]);
          S[m] += q0 * bf2f((ushort)(v.x & 0xffff)) + q1 * bf2f((ushort)(v.x >> 16))
                + q2 * bf2f((ushort)(v.y & 0xffff)) + q3 * bf2f((ushort)(v.y >> 16));
        }
      }
      float mx = S[0] * 0.0625f;
#pragma unroll
      for (int m = 1; m < 5; ++m) mx = fmaxf(mx, S[m] * 0.0625f);
      float e[5], sum = 0.f;
#pragma unroll
      for (int m = 0; m < 5; ++m) { e[m] = __expf(S[m] * 0.0625f - mx); sum += e[m]; }
      float inv = 1.0f / sum;
#pragma unroll
      for (int m = 0; m < 5; ++m) sc[sample * 26 + u * 5 + m] = e[m] * inv;
    }
    __syncthreads();

    // ---- attention C: w[m] = 0.2 * sum_l alpha[l][m]
    if (u < 5) {
      float wsum = 0.f;
#pragma unroll
      for (int l = 0; l < 5; ++l) wsum += sc[sample * 26 + l * 5 + u];
      wgt[sample * 5 + u] = wsum * 0.2f;
    }
    __syncthreads();

    // ---- attention D: s[head*64 + u*4 .. +3] = sum_m w[m] * V[m][.]
    {
      int dbase = u * 4;
      float a0 = 0.f, a1 = 0.f, a2 = 0.f, a3 = 0.f;
#pragma unroll
      for (int m = 0; m < 5; ++m) {
        int row = sample * 5 + m;
        float wv = wgt[sample * 5 + m];
        int col = 128 + dbase;
        uint2 v = *(const uint2*)(&qkv[row * 192 + (((col >> 3) ^ (row & 7)) << 3) + (col & 7)]);
        a0 += wv * bf2f((ushort)(v.x & 0xffff));
        a1 += wv * bf2f((ushort)(v.x >> 16));
        a2 += wv * bf2f((ushort)(v.y & 0xffff));
        a3 += wv * bf2f((ushort)(v.y >> 16));
      }
      uint2 p;
      p.x = (uint)f2bf(a0) | ((uint)f2bf(a1) << 16);
      p.y = (uint)f2bf(a2) | ((uint)f2bf(a3) << 16);
      *(uint2*)(&sbuf[sample * 256 + head * 64 + dbase]) = p;
    }
    __syncthreads();   // also protects qkv reuse by next head
  }

  // ---- SE gate: r[j] = relu(b1[j] + sum_c s[c]*W1T[j][c])
  {
    float acc = b1[u];
    const float* wr = w1t + u * 256;
#pragma unroll 4
    for (int c = 0; c < 256; c += 4) {
      uint2 sv = *(const uint2*)(&sbuf[sample * 256 + c]);
      float4 wv = *(const float4*)(wr + c);
      acc += bf2f((ushort)(sv.x & 0xffff)) * wv.x + bf2f((ushort)(sv.x >> 16)) * wv.y
           + bf2f((ushort)(sv.y & 0xffff)) * wv.z + bf2f((ushort)(sv.y >> 16)) * wv.w;
    }
    float* rbuf = scratch;          // alias: sc/wgt dead now
    rbuf[sample * 16 + u] = fmaxf(acc, 0.f);
  }
  __syncthreads();

  // ---- g = sigmoid(r@W2 + b2); out = g * s   (thread u: cols u*16..u*16+15)
  {
    const float* rbuf = scratch;
    float g[16];
#pragma unroll
    for (int i = 0; i < 16; ++i) g[i] = b2[u * 16 + i];
#pragma unroll
    for (int j = 0; j < 16; ++j) {
      float rj = rbuf[sample * 16 + j];
      const float* w2r = W2 + j * 256 + u * 16;
#pragma unroll
      for (int i = 0; i < 16; i += 4) {
        float4 wv = *(const float4*)(w2r + i);
        g[i + 0] += rj * wv.x; g[i + 1] += rj * wv.y;
        g[i + 2] += rj * wv.z; g[i + 3] += rj * wv.w;
      }
    }
    float* ob = out + ((size_t)blk * 16 + sample) * 256 + u * 16;
#pragma unroll
    for (int i = 0; i < 16; i += 4) {
      int c = u * 16 + i;
      uint2 sv = *(const uint2*)(&sbuf[sample * 256 + c]);
      float4 ov;
      ov.x = sigmoidf(g[i + 0]) * bf2f((ushort)(sv.x & 0xffff));
      ov.y = sigmoidf(g[i + 1]) * bf2f((ushort)(sv.x >> 16));
      ov.z = sigmoidf(g[i + 2]) * bf2f((ushort)(sv.y & 0xffff));
      ov.w = sigmoidf(g[i + 3]) * bf2f((ushort)(sv.y >> 16));
      *(float4*)(ob + i) = ov;
    }
  }
}

extern "C" void kernel_launch(void* const* d_in, const int* in_sizes, int n_in,
                              void* d_out, int out_size, void* d_ws, size_t ws_size,
                              hipStream_t stream) {
  const float* x  = (const float*)d_in[0];
  const float* Wq = (const float*)d_in[1];
  const float* bq = (const float*)d_in[2];
  const float* Wk = (const float*)d_in[3];
  const float* bk = (const float*)d_in[4];
  const float* Wv = (const float*)d_in[5];
  const float* bv = (const float*)d_in[6];
  const float* W1 = (const float*)d_in[7];
  const float* b1 = (const float*)d_in[8];
  const float* W2 = (const float*)d_in[9];
  const float* b2 = (const float*)d_in[10];

  ushort* wb  = (ushort*)d_ws;                          // 393216 B
  float*  w1t = (float*)((char*)d_ws + 393216);         // 16384 B

  prep_kernel<<<768, 256, 0, stream>>>(Wq, Wk, Wv, W1, wb, w1t);
  fused_kernel<<<6250, 256, 0, stream>>>(x, bq, bk, bv, wb, w1t, b1, W2, b2,
                                         (float*)d_out);
}